// Round 4
// baseline (14298.328 us; speedup 1.0000x reference)
//
#include <hip/hip_runtime.h>

#define DEVI static __device__ __forceinline__

typedef float    f32x4 __attribute__((ext_vector_type(4)));
typedef _Float16 f16x8 __attribute__((ext_vector_type(8)));

static constexpr int Bn = 8, Ln = 4096, Dn = 1024, Hn = 16, DKn = 64;
static constexpr int TOPK = 8;
static constexpr float LO_SCALE = 2048.f, LO_INV = 1.f / 2048.f;

DEVI f32x4 mfma_f16(f16x8 a, f16x8 b, f32x4 c) {
    return __builtin_amdgcn_mfma_f32_16x16x32_f16(a, b, c, 0, 0, 0);
}

struct HL { _Float16 hi, lo; };
// split f32 -> f16 hi + f16 lo*2048 (lo prescaled to stay in normal range;
// MFMA may flush subnormal f16 inputs, which would kill the correction)
DEVI HL split2(float x) {
    HL r;
    r.hi = (_Float16)x;
    r.lo = (_Float16)((x - (float)r.hi) * LO_SCALE);
    return r;
}

// ---------------------------------------------------------------------------
// GEMM: C[m,n] = sum_k A[m,k] * W[n,k] + bias[n]
//   W: 1024x1024 f32 row-major (out x in), bias f32.
// MODE 0: A f16 [M][1024] (Y), plain f16 MFMA, out0 f32 [M][1024] (final)
// MODE 1: A f32, plain f16 MFMA, out0 f16 head-split [b][h][l][64]  (V)
// MODE 2: A f32, COMPENSATED hi/lo f16 MFMA (f32-accurate),
//         out0/out1 = f16 hi / f16 lo*2048, head-split [h][l][64]   (Q/K)
// grid: (M/64, 16), block: 256 (4 waves, each wave a 32x32 sub-tile)
// ---------------------------------------------------------------------------
template<int MODE>
__global__ __launch_bounds__(256) void gemm_k(
    const void* __restrict__ Av, const float* __restrict__ W,
    const float* __restrict__ bias,
    void* __restrict__ out0, void* __restrict__ out1)
{
    const int l  = threadIdx.x & 63;
    const int w  = threadIdx.x >> 6;
    const int m0 = blockIdx.x * 64 + (w & 1) * 32;
    const int n0 = blockIdx.y * 64 + (w >> 1) * 32;
    const int rr = l & 15;
    const int kf = (l >> 4) * 8;

    f32x4 acc[2][2] = {};
    f32x4 accc[2][2] = {};   // scaled-lo correction accumulator (MODE 2)
    const size_t aoff = (size_t)(m0 + rr) * Dn + kf;
    const float* Wp = W + (size_t)(n0 + rr) * Dn + kf;

    for (int k0 = 0; k0 < Dn; k0 += 32) {
        f16x8 ah[2], al[2], bh[2], bl[2];
        if (MODE == 0) {
            const _Float16* Ap = (const _Float16*)Av + aoff + k0;
            ah[0] = *(const f16x8*)(Ap);
            ah[1] = *(const f16x8*)(Ap + 16 * Dn);
        } else {
            const float* Ap = (const float*)Av + aoff + k0;
#pragma unroll
            for (int i = 0; i < 2; i++) {
                f32x4 x0 = *(const f32x4*)(Ap + i * 16 * Dn);
                f32x4 x1 = *(const f32x4*)(Ap + i * 16 * Dn + 4);
#pragma unroll
                for (int j = 0; j < 4; j++) {
                    if (MODE == 2) {
                        HL p0 = split2(x0[j]), p1 = split2(x1[j]);
                        ah[i][j] = p0.hi; al[i][j] = p0.lo;
                        ah[i][4 + j] = p1.hi; al[i][4 + j] = p1.lo;
                    } else {
                        ah[i][j]     = (_Float16)x0[j];
                        ah[i][4 + j] = (_Float16)x1[j];
                    }
                }
            }
        }
#pragma unroll
        for (int i = 0; i < 2; i++) {
            f32x4 x0 = *(const f32x4*)(Wp + k0 + i * 16 * Dn);
            f32x4 x1 = *(const f32x4*)(Wp + k0 + i * 16 * Dn + 4);
#pragma unroll
            for (int j = 0; j < 4; j++) {
                if (MODE == 2) {
                    HL p0 = split2(x0[j]), p1 = split2(x1[j]);
                    bh[i][j] = p0.hi; bl[i][j] = p0.lo;
                    bh[i][4 + j] = p1.hi; bl[i][4 + j] = p1.lo;
                } else {
                    bh[i][j]     = (_Float16)x0[j];
                    bh[i][4 + j] = (_Float16)x1[j];
                }
            }
        }
#pragma unroll
        for (int i = 0; i < 2; i++)
#pragma unroll
            for (int j = 0; j < 2; j++) {
                acc[i][j] = mfma_f16(ah[i], bh[j], acc[i][j]);
                if (MODE == 2) {
                    accc[i][j] = mfma_f16(al[i], bh[j], accc[i][j]);
                    accc[i][j] = mfma_f16(ah[i], bl[j], accc[i][j]);
                }
            }
    }
#pragma unroll
    for (int i = 0; i < 2; i++)
#pragma unroll
        for (int j = 0; j < 2; j++)
#pragma unroll
            for (int r = 0; r < 4; r++) {
                const int m = m0 + i * 16 + (l >> 4) * 4 + r;
                const int n = n0 + j * 16 + (l & 15);
                float v = acc[i][j][r];
                if (MODE == 2) v += accc[i][j][r] * LO_INV;
                v += bias[n];
                if (MODE == 0) {
                    ((float*)out0)[(size_t)m * Dn + n] = v;
                } else if (MODE == 1) {
                    size_t idx = ((size_t)((m >> 12) * Hn + (n >> 6)) * Ln
                                  + (m & (Ln - 1))) * DKn + (n & 63);
                    ((_Float16*)out0)[idx] = (_Float16)v;
                } else {
                    size_t idx = ((size_t)(n >> 6) * Ln + m) * DKn + (n & 63);
                    HL p = split2(v);
                    ((_Float16*)out0)[idx] = p.hi;
                    ((_Float16*)out1)[idx] = p.lo;
                }
            }
}

// ---------------------------------------------------------------------------
// Correlation (one batch): corr[h][t] += sum_s <Q[h,s,:], K[h,(s-t)&4095,:]>
// Q/K as f16 hi + scaled-lo pairs, layout [h][l][64]. Compensated MFMA:
// acc0 = qh*kh; acc1 = ql'*kh + qh*kl'; val = acc0 + acc1/2048.
// grid: (32 s-strips of 128 rows, 16 heads), block 256 (4 waves).
// ---------------------------------------------------------------------------
__global__ __launch_bounds__(256) void corr_k(
    const _Float16* __restrict__ Qhi, const _Float16* __restrict__ Qlo,
    const _Float16* __restrict__ Khi, const _Float16* __restrict__ Klo,
    float* __restrict__ corr /* [16][4096] of this batch */)
{
    __shared__ float bins[Ln];
    const int l  = threadIdx.x & 63;
    const int w  = threadIdx.x >> 6;
    const int h  = blockIdx.y;
    const int s0 = blockIdx.x * 128 + w * 32;

    for (int i = threadIdx.x; i < Ln; i += 256) bins[i] = 0.f;
    __syncthreads();

    const int rr = l & 15;
    const int kf = (l >> 4) * 8;
    const size_t base = (size_t)h * Ln * DKn;

    f16x8 qh[2][2], ql[2][2];
#pragma unroll
    for (int st = 0; st < 2; st++)
#pragma unroll
        for (int kh = 0; kh < 2; kh++) {
            size_t off = base + (size_t)(s0 + st * 16 + rr) * DKn + kh * 32 + kf;
            qh[st][kh] = *(const f16x8*)(Qhi + off);
            ql[st][kh] = *(const f16x8*)(Qlo + off);
        }

    for (int ut = 0; ut < 256; ut++) {
        const int u0 = ut * 16;
        const size_t koff = base + (size_t)(u0 + rr) * DKn + kf;
        f16x8 kh0 = *(const f16x8*)(Khi + koff);
        f16x8 kh1 = *(const f16x8*)(Khi + koff + 32);
        f16x8 kl0 = *(const f16x8*)(Klo + koff);
        f16x8 kl1 = *(const f16x8*)(Klo + koff + 32);
#pragma unroll
        for (int st = 0; st < 2; st++) {
            f32x4 a0 = {}, a1 = {};
            a0 = mfma_f16(qh[st][0], kh0, a0);
            a0 = mfma_f16(qh[st][1], kh1, a0);
            a1 = mfma_f16(ql[st][0], kh0, a1);
            a1 = mfma_f16(qh[st][0], kl0, a1);
            a1 = mfma_f16(ql[st][1], kh1, a1);
            a1 = mfma_f16(qh[st][1], kl1, a1);
            const int s_base = s0 + st * 16 + (l >> 4) * 4;
            const int u = u0 + rr;
#pragma unroll
            for (int r = 0; r < 4; r++) {
                int t = (s_base + r - u) & (Ln - 1);
                atomicAdd(&bins[t], a0[r] + a1[r] * LO_INV);
            }
        }
    }
    __syncthreads();
    float* cg = corr + (size_t)h * Ln;
    for (int i = threadIdx.x; i < Ln; i += 256)
        atomicAdd(&cg[i], bins[i]);
}

// ---------------------------------------------------------------------------
// Top-8 + softmax per (b,h) row of corr (raw sums; /64 before softmax).
// ---------------------------------------------------------------------------
__global__ __launch_bounds__(256) void topk_k(
    const float* __restrict__ corr, float* __restrict__ top_w,
    int* __restrict__ top_idx)
{
    __shared__ float vals[Ln];
    __shared__ float rv[256];
    __shared__ int   ri[256];
    __shared__ float sel_v[TOPK];
    __shared__ int   sel_i[TOPK];
    const int bh = blockIdx.x;
    const float* c = corr + (size_t)bh * Ln;
    for (int i = threadIdx.x; i < Ln; i += 256) vals[i] = c[i];
    __syncthreads();

    for (int it = 0; it < TOPK; it++) {
        float bvv = -1e30f; int bi = 0;
        const int base = threadIdx.x * 16;
#pragma unroll
        for (int j = 0; j < 16; j++) {
            float v = vals[base + j];
            if (v > bvv) { bvv = v; bi = base + j; }
        }
        rv[threadIdx.x] = bvv; ri[threadIdx.x] = bi;
        __syncthreads();
        if (threadIdx.x == 0) {
            float gv = rv[0]; int gi = ri[0];
            for (int t = 1; t < 256; t++)
                if (rv[t] > gv) { gv = rv[t]; gi = ri[t]; }
            sel_v[it] = gv; sel_i[it] = gi;
            vals[gi] = -1e30f;
        }
        __syncthreads();
    }
    if (threadIdx.x == 0) {
        float e[TOPK], s = 0.f;
        for (int i = 0; i < TOPK; i++) {
            e[i] = expf((sel_v[i] - sel_v[0]) * (1.f / 64.f));
            s += e[i];
        }
        for (int i = 0; i < TOPK; i++) {
            top_w[bh * TOPK + i]   = e[i] / s;
            top_idx[bh * TOPK + i] = sel_i[i];
        }
    }
}

// ---------------------------------------------------------------------------
// Aggregation: Y[b][t][h*64+d] = sum_i w_i * V[b][h][(t-idx_i)&4095][d]
// V f16 head-split, Y f16 row-major. grid: (64 t-chunks, 128 bh); block 256.
// ---------------------------------------------------------------------------
__global__ __launch_bounds__(256) void agg_k(
    const _Float16* __restrict__ V /* [B][H][L][64] */,
    const float* __restrict__ top_w, const int* __restrict__ top_idx,
    _Float16* __restrict__ Y /* [B][L][1024] */)
{
    __shared__ float w_s[TOPK];
    __shared__ int   i_s[TOPK];
    const int bh   = blockIdx.y;
    const int b    = bh >> 4, h = bh & 15;
    const int tloc = threadIdx.x >> 2;
    const int c16  = (threadIdx.x & 3) * 16;
    const int t    = blockIdx.x * 64 + tloc;
    if (threadIdx.x < TOPK) {
        w_s[threadIdx.x] = top_w[bh * TOPK + threadIdx.x];
        i_s[threadIdx.x] = top_idx[bh * TOPK + threadIdx.x];
    }
    __syncthreads();

    const _Float16* Vb = V + (size_t)bh * Ln * DKn;
    float acc[16] = {};
#pragma unroll
    for (int i = 0; i < TOPK; i++) {
        const int src = (t - i_s[i]) & (Ln - 1);
        const _Float16* p = Vb + (size_t)src * DKn + c16;
        f16x8 v0 = *(const f16x8*)(p);
        f16x8 v1 = *(const f16x8*)(p + 8);
        const float wgt = w_s[i];
#pragma unroll
        for (int j = 0; j < 8; j++) acc[j]     += wgt * (float)v0[j];
#pragma unroll
        for (int j = 0; j < 8; j++) acc[8 + j] += wgt * (float)v1[j];
    }
    f16x8 o0, o1;
#pragma unroll
    for (int j = 0; j < 8; j++) { o0[j] = (_Float16)acc[j]; o1[j] = (_Float16)acc[8 + j]; }
    const size_t oidx = ((size_t)(b * Ln + t)) * Dn + h * DKn + c16;
    *(f16x8*)(Y + oidx)     = o0;
    *(f16x8*)(Y + oidx + 8) = o1;
}

// ---------------------------------------------------------------------------
extern "C" void kernel_launch(void* const* d_in, const int* in_sizes, int n_in,
                              void* d_out, int out_size, void* d_ws, size_t ws_size,
                              hipStream_t stream)
{
    const float* q  = (const float*)d_in[0];
    const float* kk = (const float*)d_in[1];
    const float* v  = (const float*)d_in[2];
    const float* Wq = (const float*)d_in[3];
    const float* bq = (const float*)d_in[4];
    const float* Wk = (const float*)d_in[5];
    const float* bk = (const float*)d_in[6];
    const float* Wv = (const float*)d_in[7];
    const float* bv = (const float*)d_in[8];
    const float* Wo = (const float*)d_in[9];
    const float* bo = (const float*)d_in[10];
    float* out = (float*)d_out;

    // ws layout (bytes):
    //   Y    f16 [B][L][D]           @ 0          (67,108,864)
    //   Qhi  f16 [H][L][64] (1 b)    @ 67108864   ( 8,388,608)
    //   Qlo                          @ 75497472
    //   Khi                          @ 83886080
    //   Klo                          @ 92274688
    //   corr f32 [B][H][L]           @ 100663296  ( 2,097,152)
    //   topw f32 [128][8]            @ 102760448
    //   topi i32 [128][8]            @ 102764544
    char* ws = (char*)d_ws;
    if (ws_size < 102768640ull) return;
    _Float16* Y   = (_Float16*)(ws);
    _Float16* Qhi = (_Float16*)(ws + 67108864);
    _Float16* Qlo = (_Float16*)(ws + 75497472);
    _Float16* Khi = (_Float16*)(ws + 83886080);
    _Float16* Klo = (_Float16*)(ws + 92274688);
    float*    corr = (float*)(ws + 100663296);
    float*    topw = (float*)(ws + 102760448);
    int*      topi = (int*)(ws + 102764544);

    (void)hipMemsetAsync(corr, 0, (size_t)Bn * Hn * Ln * sizeof(float), stream);

    // V projection staged (f16, head-split) in the first half of d_out;
    // overwritten by the final f32 projection at the end.
    _Float16* Vstage = (_Float16*)d_out;
    gemm_k<1><<<dim3(512, 16), 256, 0, stream>>>(v, Wv, bv, Vstage, nullptr);

    for (int b = 0; b < Bn; b++) {
        gemm_k<2><<<dim3(64, 16), 256, 0, stream>>>(q  + (size_t)b * Ln * Dn, Wq, bq, Qhi, Qlo);
        gemm_k<2><<<dim3(64, 16), 256, 0, stream>>>(kk + (size_t)b * Ln * Dn, Wk, bk, Khi, Klo);
        corr_k<<<dim3(32, 16), 256, 0, stream>>>(Qhi, Qlo, Khi, Klo, corr + (size_t)b * Hn * Ln);
    }
    topk_k<<<128, 256, 0, stream>>>(corr, topw, topi);
    agg_k<<<dim3(64, 128), 256, 0, stream>>>(Vstage, topw, topi, Y);
    gemm_k<0><<<dim3(512, 16), 256, 0, stream>>>(Y, Wo, bo, out, nullptr);
}

// Round 5
// 10774.454 us; speedup vs baseline: 1.3271x; 1.3271x over previous
//
#include <hip/hip_runtime.h>

#define DEVI static __device__ __forceinline__

typedef float    f32x4 __attribute__((ext_vector_type(4)));
typedef _Float16 f16x8 __attribute__((ext_vector_type(8)));

static constexpr int Bn = 8, Ln = 4096, Dn = 1024, Hn = 16, DKn = 64;
static constexpr int TOPK = 8;
static constexpr float LO_SCALE = 2048.f, LO_INV = 1.f / 2048.f;

DEVI f32x4 mfma_f16(f16x8 a, f16x8 b, f32x4 c) {
    return __builtin_amdgcn_mfma_f32_16x16x32_f16(a, b, c, 0, 0, 0);
}

struct HL { _Float16 hi, lo; };
// split f32 -> f16 hi + f16 lo*2048 (lo prescaled to stay in normal range;
// MFMA may flush subnormal f16 inputs, which would kill the correction)
DEVI HL split2(float x) {
    HL r;
    r.hi = (_Float16)x;
    r.lo = (_Float16)((x - (float)r.hi) * LO_SCALE);
    return r;
}

// ---------------------------------------------------------------------------
// GEMM body: C[m,n] = sum_k A[m,k] * W[n,k] + bias[n]
//   W: 1024x1024 f32 row-major (out x in), bias f32.
// MODE 0: A f16 [M][1024] (Y), plain f16 MFMA, out0 f32 [M][1024] (final)
// MODE 1: A f32, plain f16 MFMA, out0 f16 head-split [b][h][l][64]  (V)
// MODE 2: A f32, COMPENSATED hi/lo f16 MFMA (f32-accurate),
//         out0/out1 = f16 hi / f16 lo*2048, head-split [h][l][64]   (Q/K)
// grid x,y: (M/64, 16), block: 256 (4 waves, each wave a 32x32 sub-tile)
// ---------------------------------------------------------------------------
template<int MODE>
DEVI void gemm_body(
    const void* __restrict__ Av, const float* __restrict__ W,
    const float* __restrict__ bias,
    void* __restrict__ out0, void* __restrict__ out1)
{
    const int l  = threadIdx.x & 63;
    const int w  = threadIdx.x >> 6;
    const int m0 = blockIdx.x * 64 + (w & 1) * 32;
    const int n0 = blockIdx.y * 64 + (w >> 1) * 32;
    const int rr = l & 15;
    const int kf = (l >> 4) * 8;

    f32x4 acc[2][2] = {};
    f32x4 accc[2][2] = {};   // scaled-lo correction accumulator (MODE 2)
    const size_t aoff = (size_t)(m0 + rr) * Dn + kf;
    const float* Wp = W + (size_t)(n0 + rr) * Dn + kf;

    for (int k0 = 0; k0 < Dn; k0 += 32) {
        f16x8 ah[2], al[2], bh[2], bl[2];
        if (MODE == 0) {
            const _Float16* Ap = (const _Float16*)Av + aoff + k0;
            ah[0] = *(const f16x8*)(Ap);
            ah[1] = *(const f16x8*)(Ap + 16 * Dn);
        } else {
            const float* Ap = (const float*)Av + aoff + k0;
#pragma unroll
            for (int i = 0; i < 2; i++) {
                f32x4 x0 = *(const f32x4*)(Ap + i * 16 * Dn);
                f32x4 x1 = *(const f32x4*)(Ap + i * 16 * Dn + 4);
#pragma unroll
                for (int j = 0; j < 4; j++) {
                    if (MODE == 2) {
                        HL p0 = split2(x0[j]), p1 = split2(x1[j]);
                        ah[i][j] = p0.hi; al[i][j] = p0.lo;
                        ah[i][4 + j] = p1.hi; al[i][4 + j] = p1.lo;
                    } else {
                        ah[i][j]     = (_Float16)x0[j];
                        ah[i][4 + j] = (_Float16)x1[j];
                    }
                }
            }
        }
#pragma unroll
        for (int i = 0; i < 2; i++) {
            f32x4 x0 = *(const f32x4*)(Wp + k0 + i * 16 * Dn);
            f32x4 x1 = *(const f32x4*)(Wp + k0 + i * 16 * Dn + 4);
#pragma unroll
            for (int j = 0; j < 4; j++) {
                if (MODE == 2) {
                    HL p0 = split2(x0[j]), p1 = split2(x1[j]);
                    bh[i][j] = p0.hi; bl[i][j] = p0.lo;
                    bh[i][4 + j] = p1.hi; bl[i][4 + j] = p1.lo;
                } else {
                    bh[i][j]     = (_Float16)x0[j];
                    bh[i][4 + j] = (_Float16)x1[j];
                }
            }
        }
#pragma unroll
        for (int i = 0; i < 2; i++)
#pragma unroll
            for (int j = 0; j < 2; j++) {
                acc[i][j] = mfma_f16(ah[i], bh[j], acc[i][j]);
                if (MODE == 2) {
                    accc[i][j] = mfma_f16(al[i], bh[j], accc[i][j]);
                    accc[i][j] = mfma_f16(ah[i], bl[j], accc[i][j]);
                }
            }
    }
#pragma unroll
    for (int i = 0; i < 2; i++)
#pragma unroll
        for (int j = 0; j < 2; j++)
#pragma unroll
            for (int r = 0; r < 4; r++) {
                const int m = m0 + i * 16 + (l >> 4) * 4 + r;
                const int n = n0 + j * 16 + (l & 15);
                float v = acc[i][j][r];
                if (MODE == 2) v += accc[i][j][r] * LO_INV;
                v += bias[n];
                if (MODE == 0) {
                    ((float*)out0)[(size_t)m * Dn + n] = v;
                } else if (MODE == 1) {
                    size_t idx = ((size_t)((m >> 12) * Hn + (n >> 6)) * Ln
                                  + (m & (Ln - 1))) * DKn + (n & 63);
                    ((_Float16*)out0)[idx] = (_Float16)v;
                } else {
                    size_t idx = ((size_t)(n >> 6) * Ln + m) * DKn + (n & 63);
                    HL p = split2(v);
                    ((_Float16*)out0)[idx] = p.hi;
                    ((_Float16*)out1)[idx] = p.lo;
                }
            }
}

template<int MODE>
__global__ __launch_bounds__(256) void gemm_k(
    const void* __restrict__ Av, const float* __restrict__ W,
    const float* __restrict__ bias,
    void* __restrict__ out0, void* __restrict__ out1)
{
    gemm_body<MODE>(Av, W, bias, out0, out1);
}

// Fused Q+K projection for one batch: blockIdx.z = 0 -> Q, 1 -> K.
__global__ __launch_bounds__(256) void gemm_qk_k(
    const float* __restrict__ xq, const float* __restrict__ xk,
    const float* __restrict__ Wq, const float* __restrict__ bq,
    const float* __restrict__ Wk, const float* __restrict__ bk,
    _Float16* __restrict__ Qhi, _Float16* __restrict__ Qlo,
    _Float16* __restrict__ Khi, _Float16* __restrict__ Klo)
{
    const bool isk = blockIdx.z != 0;
    gemm_body<2>(isk ? (const void*)xk : (const void*)xq,
                 isk ? Wk : Wq, isk ? bk : bq,
                 isk ? (void*)Khi : (void*)Qhi,
                 isk ? (void*)Klo : (void*)Qlo);
}

// ---------------------------------------------------------------------------
// Correlation v2 (one batch): corr[h][t0+dtl] = sum_s <Q[h,s,:], K[h,s-t0-dtl,:]>
// Diagonal-band register accumulation — NO per-element scatter.
// Block = (band of 16 diagonals, head). 4 waves; wave w owns si in [w*64,w*64+64).
// Per si two MFMA tiles: T1 = Q[si] x K[(si*16+b-t0)%L]     (dtl = a-b,  a>=b)
//                        T2 = Q[si] x K[((si-1)*16+b-t0)%L] (dtl = 16+a-b, b>a)
// T2's K tile == previous iteration's T1 K tile (register reuse).
// Each (lane,reg) C element has a FIXED dtl -> accumulate in registers over
// all si; one tiny LDS reduce at the end; direct global write (no atomics).
// Compensated hi/lo f16 throughout (3-term).
// grid: (256 bands, 16 heads), block 256.
// ---------------------------------------------------------------------------
__global__ __launch_bounds__(256) void corr_k(
    const _Float16* __restrict__ Qhi, const _Float16* __restrict__ Qlo,
    const _Float16* __restrict__ Khi, const _Float16* __restrict__ Klo,
    float* __restrict__ corr /* [16][4096] of this batch */)
{
    __shared__ float red[16];
    const int l  = threadIdx.x & 63;
    const int w  = threadIdx.x >> 6;
    const int h  = blockIdx.y;
    const int t0 = blockIdx.x * 16;
    const int rr = l & 15;
    const int kf = (l >> 4) * 8;
    const size_t base = (size_t)h * Ln * DKn;

    if (threadIdx.x < 16) red[threadIdx.x] = 0.f;
    __syncthreads();

    f32x4 p0 = {}, p1 = {};   // T1: hh, comp
    f32x4 q0 = {}, q1 = {};   // T2: hh, comp

    // prologue: K tile for si-1 of the first si
    int pkr = ((w * 64 - 1) * 16 + rr - t0) & (Ln - 1);
    size_t pko = base + (size_t)pkr * DKn + kf;
    f16x8 pkh0 = *(const f16x8*)(Khi + pko);
    f16x8 pkh1 = *(const f16x8*)(Khi + pko + 32);
    f16x8 pkl0 = *(const f16x8*)(Klo + pko);
    f16x8 pkl1 = *(const f16x8*)(Klo + pko + 32);

    for (int si = w * 64; si < w * 64 + 64; si++) {
        const size_t qoff = base + (size_t)(si * 16 + rr) * DKn + kf;
        f16x8 qh0 = *(const f16x8*)(Qhi + qoff);
        f16x8 qh1 = *(const f16x8*)(Qhi + qoff + 32);
        f16x8 ql0 = *(const f16x8*)(Qlo + qoff);
        f16x8 ql1 = *(const f16x8*)(Qlo + qoff + 32);

        const int kr = (si * 16 + rr - t0) & (Ln - 1);
        const size_t koff = base + (size_t)kr * DKn + kf;
        f16x8 kh0 = *(const f16x8*)(Khi + koff);
        f16x8 kh1 = *(const f16x8*)(Khi + koff + 32);
        f16x8 kl0 = *(const f16x8*)(Klo + koff);
        f16x8 kl1 = *(const f16x8*)(Klo + koff + 32);

        // T1 (current K tile)
        p0 = mfma_f16(qh0, kh0, p0);
        p0 = mfma_f16(qh1, kh1, p0);
        p1 = mfma_f16(ql0, kh0, p1);
        p1 = mfma_f16(qh0, kl0, p1);
        p1 = mfma_f16(ql1, kh1, p1);
        p1 = mfma_f16(qh1, kl1, p1);
        // T2 (previous K tile)
        q0 = mfma_f16(qh0, pkh0, q0);
        q0 = mfma_f16(qh1, pkh1, q0);
        q1 = mfma_f16(ql0, pkh0, q1);
        q1 = mfma_f16(qh0, pkl0, q1);
        q1 = mfma_f16(ql1, pkh1, q1);
        q1 = mfma_f16(qh1, pkl1, q1);

        pkh0 = kh0; pkh1 = kh1; pkl0 = kl0; pkl1 = kl1;
    }

    const int bp = rr;                       // C col = K row within tile
#pragma unroll
    for (int r = 0; r < 4; r++) {
        const int ap = (l >> 4) * 4 + r;     // C row = Q row within tile
        const float v = (ap >= bp) ? (p0[r] + p1[r] * LO_INV)
                                   : (q0[r] + q1[r] * LO_INV);
        atomicAdd(&red[(ap - bp) & 15], v);
    }
    __syncthreads();
    if (threadIdx.x < 16)
        corr[(size_t)h * Ln + t0 + threadIdx.x] = red[threadIdx.x];
}

// ---------------------------------------------------------------------------
// Top-8 + softmax per (b,h) row of corr (raw sums; /64 before softmax).
// ---------------------------------------------------------------------------
__global__ __launch_bounds__(256) void topk_k(
    const float* __restrict__ corr, float* __restrict__ top_w,
    int* __restrict__ top_idx)
{
    __shared__ float vals[Ln];
    __shared__ float rv[256];
    __shared__ int   ri[256];
    __shared__ float sel_v[TOPK];
    __shared__ int   sel_i[TOPK];
    const int bh = blockIdx.x;
    const float* c = corr + (size_t)bh * Ln;
    for (int i = threadIdx.x; i < Ln; i += 256) vals[i] = c[i];
    __syncthreads();

    for (int it = 0; it < TOPK; it++) {
        float bvv = -1e30f; int bi = 0;
        const int base = threadIdx.x * 16;
#pragma unroll
        for (int j = 0; j < 16; j++) {
            float v = vals[base + j];
            if (v > bvv) { bvv = v; bi = base + j; }
        }
        rv[threadIdx.x] = bvv; ri[threadIdx.x] = bi;
        __syncthreads();
        if (threadIdx.x == 0) {
            float gv = rv[0]; int gi = ri[0];
            for (int t = 1; t < 256; t++)
                if (rv[t] > gv) { gv = rv[t]; gi = ri[t]; }
            sel_v[it] = gv; sel_i[it] = gi;
            vals[gi] = -1e30f;
        }
        __syncthreads();
    }
    if (threadIdx.x == 0) {
        float e[TOPK], s = 0.f;
        for (int i = 0; i < TOPK; i++) {
            e[i] = expf((sel_v[i] - sel_v[0]) * (1.f / 64.f));
            s += e[i];
        }
        for (int i = 0; i < TOPK; i++) {
            top_w[bh * TOPK + i]   = e[i] / s;
            top_idx[bh * TOPK + i] = sel_i[i];
        }
    }
}

// ---------------------------------------------------------------------------
// Aggregation: Y[b][t][h*64+d] = sum_i w_i * V[b][h][(t-idx_i)&4095][d]
// V f16 head-split, Y f16 row-major. grid: (64 t-chunks, 128 bh); block 256.
// ---------------------------------------------------------------------------
__global__ __launch_bounds__(256) void agg_k(
    const _Float16* __restrict__ V /* [B][H][L][64] */,
    const float* __restrict__ top_w, const int* __restrict__ top_idx,
    _Float16* __restrict__ Y /* [B][L][1024] */)
{
    __shared__ float w_s[TOPK];
    __shared__ int   i_s[TOPK];
    const int bh   = blockIdx.y;
    const int b    = bh >> 4, h = bh & 15;
    const int tloc = threadIdx.x >> 2;
    const int c16  = (threadIdx.x & 3) * 16;
    const int t    = blockIdx.x * 64 + tloc;
    if (threadIdx.x < TOPK) {
        w_s[threadIdx.x] = top_w[bh * TOPK + threadIdx.x];
        i_s[threadIdx.x] = top_idx[bh * TOPK + threadIdx.x];
    }
    __syncthreads();

    const _Float16* Vb = V + (size_t)bh * Ln * DKn;
    float acc[16] = {};
#pragma unroll
    for (int i = 0; i < TOPK; i++) {
        const int src = (t - i_s[i]) & (Ln - 1);
        const _Float16* p = Vb + (size_t)src * DKn + c16;
        f16x8 v0 = *(const f16x8*)(p);
        f16x8 v1 = *(const f16x8*)(p + 8);
        const float wgt = w_s[i];
#pragma unroll
        for (int j = 0; j < 8; j++) acc[j]     += wgt * (float)v0[j];
#pragma unroll
        for (int j = 0; j < 8; j++) acc[8 + j] += wgt * (float)v1[j];
    }
    f16x8 o0, o1;
#pragma unroll
    for (int j = 0; j < 8; j++) { o0[j] = (_Float16)acc[j]; o1[j] = (_Float16)acc[8 + j]; }
    const size_t oidx = ((size_t)(b * Ln + t)) * Dn + h * DKn + c16;
    *(f16x8*)(Y + oidx)     = o0;
    *(f16x8*)(Y + oidx + 8) = o1;
}

// ---------------------------------------------------------------------------
extern "C" void kernel_launch(void* const* d_in, const int* in_sizes, int n_in,
                              void* d_out, int out_size, void* d_ws, size_t ws_size,
                              hipStream_t stream)
{
    const float* q  = (const float*)d_in[0];
    const float* kk = (const float*)d_in[1];
    const float* v  = (const float*)d_in[2];
    const float* Wq = (const float*)d_in[3];
    const float* bq = (const float*)d_in[4];
    const float* Wk = (const float*)d_in[5];
    const float* bk = (const float*)d_in[6];
    const float* Wv = (const float*)d_in[7];
    const float* bv = (const float*)d_in[8];
    const float* Wo = (const float*)d_in[9];
    const float* bo = (const float*)d_in[10];
    float* out = (float*)d_out;

    // ws layout (bytes):
    //   Y    f16 [B][L][D]           @ 0          (67,108,864)
    //   Qhi  f16 [H][L][64] (1 b)    @ 67108864   ( 8,388,608)
    //   Qlo                          @ 75497472
    //   Khi                          @ 83886080
    //   Klo                          @ 92274688
    //   corr f32 [B][H][L]           @ 100663296  ( 2,097,152)
    //   topw f32 [128][8]            @ 102760448
    //   topi i32 [128][8]            @ 102764544
    char* ws = (char*)d_ws;
    if (ws_size < 102768640ull) return;
    _Float16* Y   = (_Float16*)(ws);
    _Float16* Qhi = (_Float16*)(ws + 67108864);
    _Float16* Qlo = (_Float16*)(ws + 75497472);
    _Float16* Khi = (_Float16*)(ws + 83886080);
    _Float16* Klo = (_Float16*)(ws + 92274688);
    float*    corr = (float*)(ws + 100663296);
    float*    topw = (float*)(ws + 102760448);
    int*      topi = (int*)(ws + 102764544);

    // V projection staged (f16, head-split) in the first half of d_out;
    // overwritten by the final f32 projection at the end.
    _Float16* Vstage = (_Float16*)d_out;
    gemm_k<1><<<dim3(512, 16), 256, 0, stream>>>(v, Wv, bv, Vstage, nullptr);

    for (int b = 0; b < Bn; b++) {
        gemm_qk_k<<<dim3(64, 16, 2), 256, 0, stream>>>(
            q + (size_t)b * Ln * Dn, kk + (size_t)b * Ln * Dn,
            Wq, bq, Wk, bk, Qhi, Qlo, Khi, Klo);
        corr_k<<<dim3(256, 16), 256, 0, stream>>>(
            Qhi, Qlo, Khi, Klo, corr + (size_t)b * Hn * Ln);
    }
    topk_k<<<128, 256, 0, stream>>>(corr, topw, topi);
    agg_k<<<dim3(64, 128), 256, 0, stream>>>(Vstage, topw, topi, Y);
    gemm_k<0><<<dim3(512, 16), 256, 0, stream>>>(Y, Wo, bo, out, nullptr);
}

// Round 6
// 5555.846 us; speedup vs baseline: 2.5736x; 1.9393x over previous
//
#include <hip/hip_runtime.h>

#define DEVI static __device__ __forceinline__

typedef float    f32x4 __attribute__((ext_vector_type(4)));
typedef _Float16 f16x8 __attribute__((ext_vector_type(8)));

static constexpr int Bn = 8, Ln = 4096, Dn = 1024, Hn = 16, DKn = 64;
static constexpr int TOPK = 8;
static constexpr float LO_SCALE = 2048.f, LO_INV = 1.f / 2048.f;

DEVI f32x4 mfma_f16(f16x8 a, f16x8 b, f32x4 c) {
    return __builtin_amdgcn_mfma_f32_16x16x32_f16(a, b, c, 0, 0, 0);
}

struct HL { _Float16 hi, lo; };
// split f32 -> f16 hi + f16 lo*2048 (lo prescaled to stay in normal range;
// MFMA may flush subnormal f16 inputs, which would kill the correction)
DEVI HL split2(float x) {
    HL r;
    r.hi = (_Float16)x;
    r.lo = (_Float16)((x - (float)r.hi) * LO_SCALE);
    return r;
}

// ---------------------------------------------------------------------------
// GEMM body: C[m,n] = sum_k A[m,k] * W[n,k] + bias[n]
//   W: 1024x1024 f32 row-major (out x in), bias f32.
// MODE 0: A f16 [M][1024] (Y), plain f16 MFMA, out0 f32 [M][1024] (final)
// MODE 1: A f32, plain f16 MFMA, out0 f16 head-split [b][h][l][64]  (V)
// MODE 2: A f32, COMPENSATED hi/lo f16 MFMA (f32-accurate),
//         out0/out1 = f16 hi / f16 lo*2048, head-split [h][l][64]   (Q/K)
// grid x,y: (M/64, 16), block: 256 (4 waves, each wave a 32x32 sub-tile)
// ---------------------------------------------------------------------------
template<int MODE>
DEVI void gemm_body(
    const void* __restrict__ Av, const float* __restrict__ W,
    const float* __restrict__ bias,
    void* __restrict__ out0, void* __restrict__ out1)
{
    const int l  = threadIdx.x & 63;
    const int w  = threadIdx.x >> 6;
    const int m0 = blockIdx.x * 64 + (w & 1) * 32;
    const int n0 = blockIdx.y * 64 + (w >> 1) * 32;
    const int rr = l & 15;
    const int kf = (l >> 4) * 8;

    f32x4 acc[2][2] = {};
    f32x4 accc[2][2] = {};   // scaled-lo correction accumulator (MODE 2)
    const size_t aoff = (size_t)(m0 + rr) * Dn + kf;
    const float* Wp = W + (size_t)(n0 + rr) * Dn + kf;

    for (int k0 = 0; k0 < Dn; k0 += 32) {
        f16x8 ah[2], al[2], bh[2], bl[2];
        if (MODE == 0) {
            const _Float16* Ap = (const _Float16*)Av + aoff + k0;
            ah[0] = *(const f16x8*)(Ap);
            ah[1] = *(const f16x8*)(Ap + 16 * Dn);
        } else {
            const float* Ap = (const float*)Av + aoff + k0;
#pragma unroll
            for (int i = 0; i < 2; i++) {
                f32x4 x0 = *(const f32x4*)(Ap + i * 16 * Dn);
                f32x4 x1 = *(const f32x4*)(Ap + i * 16 * Dn + 4);
#pragma unroll
                for (int j = 0; j < 4; j++) {
                    if (MODE == 2) {
                        HL p0 = split2(x0[j]), p1 = split2(x1[j]);
                        ah[i][j] = p0.hi; al[i][j] = p0.lo;
                        ah[i][4 + j] = p1.hi; al[i][4 + j] = p1.lo;
                    } else {
                        ah[i][j]     = (_Float16)x0[j];
                        ah[i][4 + j] = (_Float16)x1[j];
                    }
                }
            }
        }
#pragma unroll
        for (int i = 0; i < 2; i++) {
            f32x4 x0 = *(const f32x4*)(Wp + k0 + i * 16 * Dn);
            f32x4 x1 = *(const f32x4*)(Wp + k0 + i * 16 * Dn + 4);
#pragma unroll
            for (int j = 0; j < 4; j++) {
                if (MODE == 2) {
                    HL p0 = split2(x0[j]), p1 = split2(x1[j]);
                    bh[i][j] = p0.hi; bl[i][j] = p0.lo;
                    bh[i][4 + j] = p1.hi; bl[i][4 + j] = p1.lo;
                } else {
                    bh[i][j]     = (_Float16)x0[j];
                    bh[i][4 + j] = (_Float16)x1[j];
                }
            }
        }
#pragma unroll
        for (int i = 0; i < 2; i++)
#pragma unroll
            for (int j = 0; j < 2; j++) {
                acc[i][j] = mfma_f16(ah[i], bh[j], acc[i][j]);
                if (MODE == 2) {
                    accc[i][j] = mfma_f16(al[i], bh[j], accc[i][j]);
                    accc[i][j] = mfma_f16(ah[i], bl[j], accc[i][j]);
                }
            }
    }
#pragma unroll
    for (int i = 0; i < 2; i++)
#pragma unroll
        for (int j = 0; j < 2; j++)
#pragma unroll
            for (int r = 0; r < 4; r++) {
                const int m = m0 + i * 16 + (l >> 4) * 4 + r;
                const int n = n0 + j * 16 + (l & 15);
                float v = acc[i][j][r];
                if (MODE == 2) v += accc[i][j][r] * LO_INV;
                v += bias[n];
                if (MODE == 0) {
                    ((float*)out0)[(size_t)m * Dn + n] = v;
                } else if (MODE == 1) {
                    size_t idx = ((size_t)((m >> 12) * Hn + (n >> 6)) * Ln
                                  + (m & (Ln - 1))) * DKn + (n & 63);
                    ((_Float16*)out0)[idx] = (_Float16)v;
                } else {
                    size_t idx = ((size_t)(n >> 6) * Ln + m) * DKn + (n & 63);
                    HL p = split2(v);
                    ((_Float16*)out0)[idx] = p.hi;
                    ((_Float16*)out1)[idx] = p.lo;
                }
            }
}

template<int MODE>
__global__ __launch_bounds__(256) void gemm_k(
    const void* __restrict__ Av, const float* __restrict__ W,
    const float* __restrict__ bias,
    void* __restrict__ out0, void* __restrict__ out1)
{
    gemm_body<MODE>(Av, W, bias, out0, out1);
}

// Fused Q+K projection for one batch: blockIdx.z = 0 -> Q, 1 -> K.
__global__ __launch_bounds__(256) void gemm_qk_k(
    const float* __restrict__ xq, const float* __restrict__ xk,
    const float* __restrict__ Wq, const float* __restrict__ bq,
    const float* __restrict__ Wk, const float* __restrict__ bk,
    _Float16* __restrict__ Qhi, _Float16* __restrict__ Qlo,
    _Float16* __restrict__ Khi, _Float16* __restrict__ Klo)
{
    const bool isk = blockIdx.z != 0;
    gemm_body<2>(isk ? (const void*)xk : (const void*)xq,
                 isk ? Wk : Wq, isk ? bk : bq,
                 isk ? (void*)Khi : (void*)Qhi,
                 isk ? (void*)Klo : (void*)Qlo);
}

// ---------------------------------------------------------------------------
// Correlation v3 (one batch): 64-wide diagonal band + 4-deep K register ring.
// corr[h][t0+dtl] = sum_s <Q[h,s,:], K[h,s-t0-dtl,:]>, dtl in [0,64).
// Block = (band t0 of 64 diagonals, head). 4 waves; wave w owns si in
// [w*64, w*64+64). Per si, 5 MFMA tile positions j=0..4:
//   Tj = Q[si] x K rows ((si-j)*16 - t0 + b): element (a,b) -> dtl = 16j+(a-b).
// Ring identity Tj(si+1) = T(j-1)(si): load ONLY T0 fresh each step (4 loads)
// + 4 Q loads vs 30 MFMAs across 10 independent accumulator chains.
// Lane's target slot depends on sign(d=a-b), so each tile gets its own
// accumulator; per-lane select at the end: slot i = (d>=0) ? t[i] : t[i+1],
// dtl' = (d&15) + 16i. Tiny LDS reduce (64 bins), direct global store.
// Compensated hi/lo f16 (3-term) throughout.
// grid: (64 bands, 16 heads), block 256.
// ---------------------------------------------------------------------------
__global__ __launch_bounds__(256) void corr_k(
    const _Float16* __restrict__ Qhi, const _Float16* __restrict__ Qlo,
    const _Float16* __restrict__ Khi, const _Float16* __restrict__ Klo,
    float* __restrict__ corr /* [16][4096] of this batch */)
{
    __shared__ float red[64];
    const int l  = threadIdx.x & 63;
    const int w  = threadIdx.x >> 6;
    const int h  = blockIdx.y;
    const int t0 = blockIdx.x * 64;
    const int rr = l & 15;
    const int kf = (l >> 4) * 8;
    const size_t base = (size_t)h * Ln * DKn;

    if (threadIdx.x < 64) red[threadIdx.x] = 0.f;
    __syncthreads();

    f32x4 th[5] = {};   // per-tile hh accumulators
    f32x4 tc[5] = {};   // per-tile compensation accumulators

    // K ring: ring[j-1] holds tile Tj(si) = K rows ((si-j)*16 - t0 + rr)
    f16x8 rh0[4], rh1[4], rl0[4], rl1[4];
    const int si0 = w * 64;
#pragma unroll
    for (int j = 1; j <= 4; j++) {
        int r = ((si0 - j) * 16 + rr - t0) & (Ln - 1);
        size_t o = base + (size_t)r * DKn + kf;
        rh0[j-1] = *(const f16x8*)(Khi + o);
        rh1[j-1] = *(const f16x8*)(Khi + o + 32);
        rl0[j-1] = *(const f16x8*)(Klo + o);
        rl1[j-1] = *(const f16x8*)(Klo + o + 32);
    }

#pragma unroll 4
    for (int si = si0; si < si0 + 64; si++) {
        const size_t qo = base + (size_t)(si * 16 + rr) * DKn + kf;
        f16x8 qh0 = *(const f16x8*)(Qhi + qo);
        f16x8 qh1 = *(const f16x8*)(Qhi + qo + 32);
        f16x8 ql0 = *(const f16x8*)(Qlo + qo);
        f16x8 ql1 = *(const f16x8*)(Qlo + qo + 32);

        const int kr = (si * 16 + rr - t0) & (Ln - 1);
        const size_t ko = base + (size_t)kr * DKn + kf;
        f16x8 kh0 = *(const f16x8*)(Khi + ko);
        f16x8 kh1 = *(const f16x8*)(Khi + ko + 32);
        f16x8 kl0 = *(const f16x8*)(Klo + ko);
        f16x8 kl1 = *(const f16x8*)(Klo + ko + 32);

        // j = 0 (fresh tile)
        th[0] = mfma_f16(qh0, kh0, th[0]);
        th[0] = mfma_f16(qh1, kh1, th[0]);
        tc[0] = mfma_f16(ql0, kh0, tc[0]);
        tc[0] = mfma_f16(qh0, kl0, tc[0]);
        tc[0] = mfma_f16(ql1, kh1, tc[0]);
        tc[0] = mfma_f16(qh1, kl1, tc[0]);
        // j = 1..4 (ring)
#pragma unroll
        for (int j = 1; j <= 4; j++) {
            th[j] = mfma_f16(qh0, rh0[j-1], th[j]);
            th[j] = mfma_f16(qh1, rh1[j-1], th[j]);
            tc[j] = mfma_f16(ql0, rh0[j-1], tc[j]);
            tc[j] = mfma_f16(qh0, rl0[j-1], tc[j]);
            tc[j] = mfma_f16(ql1, rh1[j-1], tc[j]);
            tc[j] = mfma_f16(qh1, rl1[j-1], tc[j]);
        }
        // rotate ring: T_{j}(si+1) = T_{j-1}(si)
#pragma unroll
        for (int j = 3; j >= 1; j--) {
            rh0[j] = rh0[j-1]; rh1[j] = rh1[j-1];
            rl0[j] = rl0[j-1]; rl1[j] = rl1[j-1];
        }
        rh0[0] = kh0; rh1[0] = kh1; rl0[0] = kl0; rl1[0] = kl1;
    }

#pragma unroll
    for (int r = 0; r < 4; r++) {
        const int d  = (l >> 4) * 4 + r - rr;   // a - b
        const int dl = d & 15;
        const bool pos = d >= 0;
#pragma unroll
        for (int i = 0; i < 4; i++) {
            const float hh = pos ? th[i][r] : th[i+1][r];
            const float cc = pos ? tc[i][r] : tc[i+1][r];
            atomicAdd(&red[dl + 16 * i], hh + cc * LO_INV);
        }
    }
    __syncthreads();
    if (threadIdx.x < 64)
        corr[(size_t)h * Ln + t0 + threadIdx.x] = red[threadIdx.x];
}

// ---------------------------------------------------------------------------
// Top-8 + softmax per (b,h) row of corr (raw sums; /64 before softmax).
// ---------------------------------------------------------------------------
__global__ __launch_bounds__(256) void topk_k(
    const float* __restrict__ corr, float* __restrict__ top_w,
    int* __restrict__ top_idx)
{
    __shared__ float vals[Ln];
    __shared__ float rv[256];
    __shared__ int   ri[256];
    __shared__ float sel_v[TOPK];
    __shared__ int   sel_i[TOPK];
    const int bh = blockIdx.x;
    const float* c = corr + (size_t)bh * Ln;
    for (int i = threadIdx.x; i < Ln; i += 256) vals[i] = c[i];
    __syncthreads();

    for (int it = 0; it < TOPK; it++) {
        float bvv = -1e30f; int bi = 0;
        const int base = threadIdx.x * 16;
#pragma unroll
        for (int j = 0; j < 16; j++) {
            float v = vals[base + j];
            if (v > bvv) { bvv = v; bi = base + j; }
        }
        rv[threadIdx.x] = bvv; ri[threadIdx.x] = bi;
        __syncthreads();
        if (threadIdx.x == 0) {
            float gv = rv[0]; int gi = ri[0];
            for (int t = 1; t < 256; t++)
                if (rv[t] > gv) { gv = rv[t]; gi = ri[t]; }
            sel_v[it] = gv; sel_i[it] = gi;
            vals[gi] = -1e30f;
        }
        __syncthreads();
    }
    if (threadIdx.x == 0) {
        float e[TOPK], s = 0.f;
        for (int i = 0; i < TOPK; i++) {
            e[i] = expf((sel_v[i] - sel_v[0]) * (1.f / 64.f));
            s += e[i];
        }
        for (int i = 0; i < TOPK; i++) {
            top_w[bh * TOPK + i]   = e[i] / s;
            top_idx[bh * TOPK + i] = sel_i[i];
        }
    }
}

// ---------------------------------------------------------------------------
// Aggregation: Y[b][t][h*64+d] = sum_i w_i * V[b][h][(t-idx_i)&4095][d]
// V f16 head-split, Y f16 row-major. grid: (64 t-chunks, 128 bh); block 256.
// ---------------------------------------------------------------------------
__global__ __launch_bounds__(256) void agg_k(
    const _Float16* __restrict__ V /* [B][H][L][64] */,
    const float* __restrict__ top_w, const int* __restrict__ top_idx,
    _Float16* __restrict__ Y /* [B][L][1024] */)
{
    __shared__ float w_s[TOPK];
    __shared__ int   i_s[TOPK];
    const int bh   = blockIdx.y;
    const int b    = bh >> 4, h = bh & 15;
    const int tloc = threadIdx.x >> 2;
    const int c16  = (threadIdx.x & 3) * 16;
    const int t    = blockIdx.x * 64 + tloc;
    if (threadIdx.x < TOPK) {
        w_s[threadIdx.x] = top_w[bh * TOPK + threadIdx.x];
        i_s[threadIdx.x] = top_idx[bh * TOPK + threadIdx.x];
    }
    __syncthreads();

    const _Float16* Vb = V + (size_t)bh * Ln * DKn;
    float acc[16] = {};
#pragma unroll
    for (int i = 0; i < TOPK; i++) {
        const int src = (t - i_s[i]) & (Ln - 1);
        const _Float16* p = Vb + (size_t)src * DKn + c16;
        f16x8 v0 = *(const f16x8*)(p);
        f16x8 v1 = *(const f16x8*)(p + 8);
        const float wgt = w_s[i];
#pragma unroll
        for (int j = 0; j < 8; j++) acc[j]     += wgt * (float)v0[j];
#pragma unroll
        for (int j = 0; j < 8; j++) acc[8 + j] += wgt * (float)v1[j];
    }
    f16x8 o0, o1;
#pragma unroll
    for (int j = 0; j < 8; j++) { o0[j] = (_Float16)acc[j]; o1[j] = (_Float16)acc[8 + j]; }
    const size_t oidx = ((size_t)(b * Ln + t)) * Dn + h * DKn + c16;
    *(f16x8*)(Y + oidx)     = o0;
    *(f16x8*)(Y + oidx + 8) = o1;
}

// ---------------------------------------------------------------------------
extern "C" void kernel_launch(void* const* d_in, const int* in_sizes, int n_in,
                              void* d_out, int out_size, void* d_ws, size_t ws_size,
                              hipStream_t stream)
{
    const float* q  = (const float*)d_in[0];
    const float* kk = (const float*)d_in[1];
    const float* v  = (const float*)d_in[2];
    const float* Wq = (const float*)d_in[3];
    const float* bq = (const float*)d_in[4];
    const float* Wk = (const float*)d_in[5];
    const float* bk = (const float*)d_in[6];
    const float* Wv = (const float*)d_in[7];
    const float* bv = (const float*)d_in[8];
    const float* Wo = (const float*)d_in[9];
    const float* bo = (const float*)d_in[10];
    float* out = (float*)d_out;

    // ws layout (bytes):
    //   Y    f16 [B][L][D]           @ 0          (67,108,864)
    //   Qhi  f16 [H][L][64] (1 b)    @ 67108864   ( 8,388,608)
    //   Qlo                          @ 75497472
    //   Khi                          @ 83886080
    //   Klo                          @ 92274688
    //   corr f32 [B][H][L]           @ 100663296  ( 2,097,152)
    //   topw f32 [128][8]            @ 102760448
    //   topi i32 [128][8]            @ 102764544
    char* ws = (char*)d_ws;
    if (ws_size < 102768640ull) return;
    _Float16* Y   = (_Float16*)(ws);
    _Float16* Qhi = (_Float16*)(ws + 67108864);
    _Float16* Qlo = (_Float16*)(ws + 75497472);
    _Float16* Khi = (_Float16*)(ws + 83886080);
    _Float16* Klo = (_Float16*)(ws + 92274688);
    float*    corr = (float*)(ws + 100663296);
    float*    topw = (float*)(ws + 102760448);
    int*      topi = (int*)(ws + 102764544);

    // V projection staged (f16, head-split) in the first half of d_out;
    // overwritten by the final f32 projection at the end.
    _Float16* Vstage = (_Float16*)d_out;
    gemm_k<1><<<dim3(512, 16), 256, 0, stream>>>(v, Wv, bv, Vstage, nullptr);

    for (int b = 0; b < Bn; b++) {
        gemm_qk_k<<<dim3(64, 16, 2), 256, 0, stream>>>(
            q + (size_t)b * Ln * Dn, kk + (size_t)b * Ln * Dn,
            Wq, bq, Wk, bk, Qhi, Qlo, Khi, Klo);
        corr_k<<<dim3(64, 16), 256, 0, stream>>>(
            Qhi, Qlo, Khi, Klo, corr + (size_t)b * Hn * Ln);
    }
    topk_k<<<128, 256, 0, stream>>>(corr, topw, topi);
    agg_k<<<dim3(64, 128), 256, 0, stream>>>(Vstage, topw, topi, Y);
    gemm_k<0><<<dim3(512, 16), 256, 0, stream>>>(Y, Wo, bo, out, nullptr);
}

// Round 7
// 3291.765 us; speedup vs baseline: 4.3437x; 1.6878x over previous
//
#include <hip/hip_runtime.h>

#define DEVI static __device__ __forceinline__

typedef float    f32x4 __attribute__((ext_vector_type(4)));
typedef _Float16 f16x8 __attribute__((ext_vector_type(8)));

static constexpr int Bn = 8, Ln = 4096, Dn = 1024, Hn = 16, DKn = 64;
static constexpr int TOPK = 8;
static constexpr float LO_SCALE = 2048.f, LO_INV = 1.f / 2048.f;

DEVI f32x4 mfma_f16(f16x8 a, f16x8 b, f32x4 c) {
    return __builtin_amdgcn_mfma_f32_16x16x32_f16(a, b, c, 0, 0, 0);
}

struct HL { _Float16 hi, lo; };
// split f32 -> f16 hi + f16 lo*2048 (prescaled so lo stays in normal f16
// range; MFMA flushes subnormal inputs which would kill the correction)
DEVI HL split2(float x) {
    HL r;
    r.hi = (_Float16)x;
    r.lo = (_Float16)((x - (float)r.hi) * LO_SCALE);
    return r;
}

// async global->LDS, 16B per lane, LDS dest = wave-uniform base + lane*16
DEVI void gload16(const void* g, void* l) {
    __builtin_amdgcn_global_load_lds(
        (const __attribute__((address_space(1))) unsigned int*)g,
        (__attribute__((address_space(3))) unsigned int*)l,
        16, 0, 0);
}

// ---------------------------------------------------------------------------
// dtype conversion kernels (one-time, memory-bound)
// ---------------------------------------------------------------------------
// f32 -> f16 hi + scaled-lo. blockIdx.y selects (A,B) stream pair.
__global__ __launch_bounds__(256) void cvt_split_k(
    const float* __restrict__ srcA, _Float16* __restrict__ hiA, _Float16* __restrict__ loA,
    const float* __restrict__ srcB, _Float16* __restrict__ hiB, _Float16* __restrict__ loB,
    int n8)
{
    const float* s  = blockIdx.y ? srcB : srcA;
    _Float16*    ph = blockIdx.y ? hiB  : hiA;
    _Float16*    pl = blockIdx.y ? loB  : loA;
    const int idx = blockIdx.x * 256 + threadIdx.x;
    if (idx >= n8) return;
    f32x4 x0 = *(const f32x4*)(s + (size_t)idx * 8);
    f32x4 x1 = *(const f32x4*)(s + (size_t)idx * 8 + 4);
    f16x8 h, l;
#pragma unroll
    for (int j = 0; j < 4; j++) {
        HL p0 = split2(x0[j]), p1 = split2(x1[j]);
        h[j] = p0.hi; l[j] = p0.lo;
        h[4 + j] = p1.hi; l[4 + j] = p1.lo;
    }
    *(f16x8*)(ph + (size_t)idx * 8) = h;
    *(f16x8*)(pl + (size_t)idx * 8) = l;
}

// f32 -> f16 plain. blockIdx.y selects (A,B).
__global__ __launch_bounds__(256) void cvt_f16_k(
    const float* __restrict__ srcA, _Float16* __restrict__ dstA,
    const float* __restrict__ srcB, _Float16* __restrict__ dstB, int n8)
{
    const float* s = blockIdx.y ? srcB : srcA;
    _Float16*    d = blockIdx.y ? dstB : dstA;
    const int idx = blockIdx.x * 256 + threadIdx.x;
    if (idx >= n8) return;
    f32x4 x0 = *(const f32x4*)(s + (size_t)idx * 8);
    f32x4 x1 = *(const f32x4*)(s + (size_t)idx * 8 + 4);
    f16x8 o;
#pragma unroll
    for (int j = 0; j < 4; j++) { o[j] = (_Float16)x0[j]; o[4 + j] = (_Float16)x1[j]; }
    *(f16x8*)(d + (size_t)idx * 8) = o;
}

// ---------------------------------------------------------------------------
// m97-structure GEMM: C[m,n] = sum_k A[m,k]*W[n,k] + bias[n], K = 1024.
// 128x128 tile, BK=32, 4 waves (each 64x64 = 4x4 fragments), LDS staging via
// global_load_lds width 16, 2-barrier K-loop. All operands f16.
// COMP: A/W have hi+scaled-lo pairs; 3-term compensated MFMA (f32-accurate).
// MODE 0: out0 f32 row-major [M][1024]              (final O-proj)
// MODE 1: out0 f16 head-split [b][h][l][64], b=m>>12 (V staging)
// MODE 2: out0/out1 f16 hi/lo head-split [h][l][64]  (Q/K, per batch)
// ---------------------------------------------------------------------------
DEVI void stage8(const _Float16* gbase, _Float16* ltile, int w, int lane, int k0) {
    // one 128x32 f16 tile (8KB) = 8 chunks of 1KB; wave w stages chunks 2w,2w+1
#pragma unroll
    for (int c = 0; c < 2; c++) {
        const int chunk = 2 * w + c;
        const int row = chunk * 16 + (lane >> 2);
        gload16(gbase + (size_t)row * Dn + k0 + (lane & 3) * 8, ltile + chunk * 512);
    }
}

template<int MODE, bool COMP>
DEVI void gemm2_body(
    const _Float16* __restrict__ A_hi, const _Float16* __restrict__ A_lo,
    const _Float16* __restrict__ W_hi, const _Float16* __restrict__ W_lo,
    const float* __restrict__ bias, void* __restrict__ out0, void* __restrict__ out1)
{
    __shared__ _Float16 lds[(COMP ? 4 : 2) * 4096];
    _Float16* sAh = lds;
    _Float16* sWh = lds + 4096;
    _Float16* sAl = COMP ? lds + 8192  : lds;
    _Float16* sWl = COMP ? lds + 12288 : lds;

    const int l  = threadIdx.x & 63;
    const int w  = threadIdx.x >> 6;
    const int m0 = blockIdx.x * 128;
    const int n0 = blockIdx.y * 128;
    const int wm = (w & 1) * 64, wn = (w >> 1) * 64;
    const int rr = l & 15, ko = (l >> 4) * 8;

    const _Float16* Abh = A_hi + (size_t)m0 * Dn;
    const _Float16* Wbh = W_hi + (size_t)n0 * Dn;
    const _Float16* Abl = COMP ? A_lo + (size_t)m0 * Dn : nullptr;
    const _Float16* Wbl = COMP ? W_lo + (size_t)n0 * Dn : nullptr;

    f32x4 acc[4][4] = {};
    f32x4 accc[4][4] = {};

    for (int k0 = 0; k0 < Dn; k0 += 32) {
        stage8(Abh, sAh, w, l, k0);
        stage8(Wbh, sWh, w, l, k0);
        if (COMP) {
            stage8(Abl, sAl, w, l, k0);
            stage8(Wbl, sWl, w, l, k0);
        }
        __syncthreads();   // drains vmcnt (gload_lds) + barrier

        f16x8 af[4], bf[4], alf[4], blf[4];
#pragma unroll
        for (int i = 0; i < 4; i++) {
            af[i] = *(const f16x8*)&sAh[(wm + 16 * i + rr) * 32 + ko];
            bf[i] = *(const f16x8*)&sWh[(wn + 16 * i + rr) * 32 + ko];
            if (COMP) {
                alf[i] = *(const f16x8*)&sAl[(wm + 16 * i + rr) * 32 + ko];
                blf[i] = *(const f16x8*)&sWl[(wn + 16 * i + rr) * 32 + ko];
            }
        }
#pragma unroll
        for (int i = 0; i < 4; i++)
#pragma unroll
            for (int j = 0; j < 4; j++) {
                acc[i][j] = mfma_f16(af[i], bf[j], acc[i][j]);
                if (COMP) {
                    accc[i][j] = mfma_f16(alf[i], bf[j], accc[i][j]);
                    accc[i][j] = mfma_f16(af[i], blf[j], accc[i][j]);
                }
            }
        __syncthreads();
    }

#pragma unroll
    for (int i = 0; i < 4; i++)
#pragma unroll
        for (int j = 0; j < 4; j++)
#pragma unroll
            for (int r = 0; r < 4; r++) {
                const int m = m0 + wm + 16 * i + (l >> 4) * 4 + r;
                const int n = n0 + wn + 16 * j + (l & 15);
                float v = acc[i][j][r];
                if (COMP) v += accc[i][j][r] * LO_INV;
                v += bias[n];
                if (MODE == 0) {
                    ((float*)out0)[(size_t)m * Dn + n] = v;
                } else if (MODE == 1) {
                    size_t idx = ((size_t)((m >> 12) * Hn + (n >> 6)) * Ln
                                  + (m & (Ln - 1))) * DKn + (n & 63);
                    ((_Float16*)out0)[idx] = (_Float16)v;
                } else {
                    size_t idx = ((size_t)(n >> 6) * Ln + m) * DKn + (n & 63);
                    HL p = split2(v);
                    ((_Float16*)out0)[idx] = p.hi;
                    ((_Float16*)out1)[idx] = p.lo;
                }
            }
}

__global__ __launch_bounds__(256) void gemm_v_k(
    const _Float16* __restrict__ xv, const _Float16* __restrict__ Wv,
    const float* __restrict__ bv, _Float16* __restrict__ Vstage)
{
    gemm2_body<1, false>(xv, nullptr, Wv, nullptr, bv, Vstage, nullptr);
}

__global__ __launch_bounds__(256) void gemm_o_k(
    const _Float16* __restrict__ Y, const _Float16* __restrict__ Wo,
    const float* __restrict__ bo, float* __restrict__ out)
{
    gemm2_body<0, false>(Y, nullptr, Wo, nullptr, bo, out, nullptr);
}

__global__ __launch_bounds__(256) void gemm_qk_k(
    const _Float16* __restrict__ xqhi, const _Float16* __restrict__ xqlo,
    const _Float16* __restrict__ xkhi, const _Float16* __restrict__ xklo,
    const _Float16* __restrict__ Wqhi, const _Float16* __restrict__ Wqlo,
    const _Float16* __restrict__ Wkhi, const _Float16* __restrict__ Wklo,
    const float* __restrict__ bq, const float* __restrict__ bk,
    _Float16* __restrict__ Qhi, _Float16* __restrict__ Qlo,
    _Float16* __restrict__ Khi, _Float16* __restrict__ Klo)
{
    if (blockIdx.z == 0)
        gemm2_body<2, true>(xqhi, xqlo, Wqhi, Wqlo, bq, Qhi, Qlo);
    else
        gemm2_body<2, true>(xkhi, xklo, Wkhi, Wklo, bk, Khi, Klo);
}

// ---------------------------------------------------------------------------
// Correlation v3 (one batch): 64-wide diagonal band + 4-deep K register ring.
// corr[h][t0+dtl] = sum_s <Q[h,s,:], K[h,s-t0-dtl,:]>, dtl in [0,64).
// grid: (64 bands, 16 heads), block 256 (4 waves, wave w owns si in [64w,64w+64)).
// ---------------------------------------------------------------------------
__global__ __launch_bounds__(256) void corr_k(
    const _Float16* __restrict__ Qhi, const _Float16* __restrict__ Qlo,
    const _Float16* __restrict__ Khi, const _Float16* __restrict__ Klo,
    float* __restrict__ corr /* [16][4096] of this batch */)
{
    __shared__ float red[64];
    const int l  = threadIdx.x & 63;
    const int w  = threadIdx.x >> 6;
    const int h  = blockIdx.y;
    const int t0 = blockIdx.x * 64;
    const int rr = l & 15;
    const int kf = (l >> 4) * 8;
    const size_t base = (size_t)h * Ln * DKn;

    if (threadIdx.x < 64) red[threadIdx.x] = 0.f;
    __syncthreads();

    f32x4 th[5] = {};
    f32x4 tc[5] = {};

    f16x8 rh0[4], rh1[4], rl0[4], rl1[4];
    const int si0 = w * 64;
#pragma unroll
    for (int j = 1; j <= 4; j++) {
        int r = ((si0 - j) * 16 + rr - t0) & (Ln - 1);
        size_t o = base + (size_t)r * DKn + kf;
        rh0[j-1] = *(const f16x8*)(Khi + o);
        rh1[j-1] = *(const f16x8*)(Khi + o + 32);
        rl0[j-1] = *(const f16x8*)(Klo + o);
        rl1[j-1] = *(const f16x8*)(Klo + o + 32);
    }

#pragma unroll 4
    for (int si = si0; si < si0 + 64; si++) {
        const size_t qo = base + (size_t)(si * 16 + rr) * DKn + kf;
        f16x8 qh0 = *(const f16x8*)(Qhi + qo);
        f16x8 qh1 = *(const f16x8*)(Qhi + qo + 32);
        f16x8 ql0 = *(const f16x8*)(Qlo + qo);
        f16x8 ql1 = *(const f16x8*)(Qlo + qo + 32);

        const int kr = (si * 16 + rr - t0) & (Ln - 1);
        const size_t koff = base + (size_t)kr * DKn + kf;
        f16x8 kh0 = *(const f16x8*)(Khi + koff);
        f16x8 kh1 = *(const f16x8*)(Khi + koff + 32);
        f16x8 kl0 = *(const f16x8*)(Klo + koff);
        f16x8 kl1 = *(const f16x8*)(Klo + koff + 32);

        th[0] = mfma_f16(qh0, kh0, th[0]);
        th[0] = mfma_f16(qh1, kh1, th[0]);
        tc[0] = mfma_f16(ql0, kh0, tc[0]);
        tc[0] = mfma_f16(qh0, kl0, tc[0]);
        tc[0] = mfma_f16(ql1, kh1, tc[0]);
        tc[0] = mfma_f16(qh1, kl1, tc[0]);
#pragma unroll
        for (int j = 1; j <= 4; j++) {
            th[j] = mfma_f16(qh0, rh0[j-1], th[j]);
            th[j] = mfma_f16(qh1, rh1[j-1], th[j]);
            tc[j] = mfma_f16(ql0, rh0[j-1], tc[j]);
            tc[j] = mfma_f16(qh0, rl0[j-1], tc[j]);
            tc[j] = mfma_f16(ql1, rh1[j-1], tc[j]);
            tc[j] = mfma_f16(qh1, rl1[j-1], tc[j]);
        }
#pragma unroll
        for (int j = 3; j >= 1; j--) {
            rh0[j] = rh0[j-1]; rh1[j] = rh1[j-1];
            rl0[j] = rl0[j-1]; rl1[j] = rl1[j-1];
        }
        rh0[0] = kh0; rh1[0] = kh1; rl0[0] = kl0; rl1[0] = kl1;
    }

#pragma unroll
    for (int r = 0; r < 4; r++) {
        const int d  = (l >> 4) * 4 + r - rr;
        const int dl = d & 15;
        const bool pos = d >= 0;
#pragma unroll
        for (int i = 0; i < 4; i++) {
            const float hh = pos ? th[i][r] : th[i+1][r];
            const float cc = pos ? tc[i][r] : tc[i+1][r];
            atomicAdd(&red[dl + 16 * i], hh + cc * LO_INV);
        }
    }
    __syncthreads();
    if (threadIdx.x < 64)
        corr[(size_t)h * Ln + t0 + threadIdx.x] = red[threadIdx.x];
}

// ---------------------------------------------------------------------------
// Top-8 + softmax per (b,h) row of corr (raw sums; /64 before softmax).
// ---------------------------------------------------------------------------
__global__ __launch_bounds__(256) void topk_k(
    const float* __restrict__ corr, float* __restrict__ top_w,
    int* __restrict__ top_idx)
{
    __shared__ float vals[Ln];
    __shared__ float rv[256];
    __shared__ int   ri[256];
    __shared__ float sel_v[TOPK];
    __shared__ int   sel_i[TOPK];
    const int bh = blockIdx.x;
    const float* c = corr + (size_t)bh * Ln;
    for (int i = threadIdx.x; i < Ln; i += 256) vals[i] = c[i];
    __syncthreads();

    for (int it = 0; it < TOPK; it++) {
        float bvv = -1e30f; int bi = 0;
        const int base = threadIdx.x * 16;
#pragma unroll
        for (int j = 0; j < 16; j++) {
            float v = vals[base + j];
            if (v > bvv) { bvv = v; bi = base + j; }
        }
        rv[threadIdx.x] = bvv; ri[threadIdx.x] = bi;
        __syncthreads();
        if (threadIdx.x == 0) {
            float gv = rv[0]; int gi = ri[0];
            for (int t = 1; t < 256; t++)
                if (rv[t] > gv) { gv = rv[t]; gi = ri[t]; }
            sel_v[it] = gv; sel_i[it] = gi;
            vals[gi] = -1e30f;
        }
        __syncthreads();
    }
    if (threadIdx.x == 0) {
        float e[TOPK], s = 0.f;
        for (int i = 0; i < TOPK; i++) {
            e[i] = expf((sel_v[i] - sel_v[0]) * (1.f / 64.f));
            s += e[i];
        }
        for (int i = 0; i < TOPK; i++) {
            top_w[bh * TOPK + i]   = e[i] / s;
            top_idx[bh * TOPK + i] = sel_i[i];
        }
    }
}

// ---------------------------------------------------------------------------
// Aggregation: Y[b][t][h*64+d] = sum_i w_i * V[b][h][(t-idx_i)&4095][d]
// ---------------------------------------------------------------------------
__global__ __launch_bounds__(256) void agg_k(
    const _Float16* __restrict__ V /* [B][H][L][64] */,
    const float* __restrict__ top_w, const int* __restrict__ top_idx,
    _Float16* __restrict__ Y /* [B][L][1024] */)
{
    __shared__ float w_s[TOPK];
    __shared__ int   i_s[TOPK];
    const int bh   = blockIdx.y;
    const int b    = bh >> 4, h = bh & 15;
    const int tloc = threadIdx.x >> 2;
    const int c16  = (threadIdx.x & 3) * 16;
    const int t    = blockIdx.x * 64 + tloc;
    if (threadIdx.x < TOPK) {
        w_s[threadIdx.x] = top_w[bh * TOPK + threadIdx.x];
        i_s[threadIdx.x] = top_idx[bh * TOPK + threadIdx.x];
    }
    __syncthreads();

    const _Float16* Vb = V + (size_t)bh * Ln * DKn;
    float acc[16] = {};
#pragma unroll
    for (int i = 0; i < TOPK; i++) {
        const int src = (t - i_s[i]) & (Ln - 1);
        const _Float16* p = Vb + (size_t)src * DKn + c16;
        f16x8 v0 = *(const f16x8*)(p);
        f16x8 v1 = *(const f16x8*)(p + 8);
        const float wgt = w_s[i];
#pragma unroll
        for (int j = 0; j < 8; j++) acc[j]     += wgt * (float)v0[j];
#pragma unroll
        for (int j = 0; j < 8; j++) acc[8 + j] += wgt * (float)v1[j];
    }
    f16x8 o0, o1;
#pragma unroll
    for (int j = 0; j < 8; j++) { o0[j] = (_Float16)acc[j]; o1[j] = (_Float16)acc[8 + j]; }
    const size_t oidx = ((size_t)(b * Ln + t)) * Dn + h * DKn + c16;
    *(f16x8*)(Y + oidx)     = o0;
    *(f16x8*)(Y + oidx + 8) = o1;
}

// ---------------------------------------------------------------------------
extern "C" void kernel_launch(void* const* d_in, const int* in_sizes, int n_in,
                              void* d_out, int out_size, void* d_ws, size_t ws_size,
                              hipStream_t stream)
{
    const float* q  = (const float*)d_in[0];
    const float* kk = (const float*)d_in[1];
    const float* v  = (const float*)d_in[2];
    const float* Wq = (const float*)d_in[3];
    const float* bq = (const float*)d_in[4];
    const float* Wk = (const float*)d_in[5];
    const float* bk = (const float*)d_in[6];
    const float* Wv = (const float*)d_in[7];
    const float* bv = (const float*)d_in[8];
    const float* Wo = (const float*)d_in[9];
    const float* bo = (const float*)d_in[10];
    float* out = (float*)d_out;

    // ws layout (bytes):
    //  region A (loop scratch; overlaid by Y after the batch loop):
    //   Qhi  @ 0         8,388,608  f16 [16][4096][64]
    //   Qlo  @ 8388608
    //   Khi  @ 16777216
    //   Klo  @ 25165824
    //   xqhi @ 33554432  8,388,608  f16 [4096][1024]
    //   xqlo @ 41943040
    //   xkhi @ 50331648
    //   xklo @ 58720256
    //   Y    @ 0        67,108,864  f16 [8][4096][1024]  (after loop)
    //  corr  @ 67108864  2,097,152  f32 [8][16][4096]
    //  topw  @ 69206016      4096
    //  topi  @ 69210112      4096
    //  Wqhi  @ 69214208  2,097,152  f16 [1024][1024]
    //  Wqlo  @ 71311360
    //  Wkhi  @ 73408512
    //  Wklo  @ 75505664
    //  Wvf   @ 77602816
    //  Wof   @ 79699968  (end 81,797,120)
    char* ws = (char*)d_ws;
    if (ws_size < 81797120ull) return;
    _Float16* Qhi  = (_Float16*)(ws);
    _Float16* Qlo  = (_Float16*)(ws + 8388608);
    _Float16* Khi  = (_Float16*)(ws + 16777216);
    _Float16* Klo  = (_Float16*)(ws + 25165824);
    _Float16* xqhi = (_Float16*)(ws + 33554432);
    _Float16* xqlo = (_Float16*)(ws + 41943040);
    _Float16* xkhi = (_Float16*)(ws + 50331648);
    _Float16* xklo = (_Float16*)(ws + 58720256);
    _Float16* Y    = (_Float16*)(ws);
    float*    corr = (float*)(ws + 67108864);
    float*    topw = (float*)(ws + 69206016);
    int*      topi = (int*)(ws + 69210112);
    _Float16* Wqhi = (_Float16*)(ws + 69214208);
    _Float16* Wqlo = (_Float16*)(ws + 71311360);
    _Float16* Wkhi = (_Float16*)(ws + 73408512);
    _Float16* Wklo = (_Float16*)(ws + 75505664);
    _Float16* Wvf  = (_Float16*)(ws + 77602816);
    _Float16* Wof  = (_Float16*)(ws + 79699968);

    // d_out (134,217,728 B): Vstage f16 [8][16][4096][64] @0, xvf16 @67108864.
    _Float16* Vstage = (_Float16*)d_out;
    _Float16* xvf16  = (_Float16*)((char*)d_out + 67108864);

    // --- one-time weight/input conversions ---
    cvt_split_k<<<dim3(512, 2), 256, 0, stream>>>(Wq, Wqhi, Wqlo, Wk, Wkhi, Wklo, 131072);
    cvt_f16_k<<<dim3(512, 2), 256, 0, stream>>>(Wv, Wvf, Wo, Wof, 131072);
    cvt_f16_k<<<dim3(16384, 1), 256, 0, stream>>>(v, xvf16, v, xvf16, 4194304);

    // V projection (f16, head-split) into low half of d_out.
    gemm_v_k<<<dim3(256, 8), 256, 0, stream>>>(xvf16, Wvf, bv, Vstage);

    for (int b = 0; b < Bn; b++) {
        cvt_split_k<<<dim3(2048, 2), 256, 0, stream>>>(
            q + (size_t)b * Ln * Dn, xqhi, xqlo,
            kk + (size_t)b * Ln * Dn, xkhi, xklo, 524288);
        gemm_qk_k<<<dim3(32, 8, 2), 256, 0, stream>>>(
            xqhi, xqlo, xkhi, xklo,
            Wqhi, Wqlo, Wkhi, Wklo, bq, bk,
            Qhi, Qlo, Khi, Klo);
        corr_k<<<dim3(64, 16), 256, 0, stream>>>(
            Qhi, Qlo, Khi, Klo, corr + (size_t)b * Hn * Ln);
    }
    topk_k<<<128, 256, 0, stream>>>(corr, topw, topi);
    agg_k<<<dim3(64, 128), 256, 0, stream>>>(Vstage, topw, topi, Y);
    gemm_o_k<<<dim3(256, 8), 256, 0, stream>>>(Y, Wof, bo, out);
}